// Round 13
// baseline (603.613 us; speedup 1.0000x reference)
//
#include <hip/hip_runtime.h>
#include <math.h>

typedef _Float16 h16;
typedef _Float16 v2h __attribute__((ext_vector_type(2)));
typedef float f4u __attribute__((ext_vector_type(4), aligned(4)));

#define ALPHA 0.2f
#define MASKV -9000000000000000.0f

// v13 = R12 (284us steady best) + acc-liveness fix:
// The ~150MB/way scratch residue is ~36 dwords/lane-iter, symmetric — a
// fixed spill set. Pressure audit: F+G holds acc[9][6]=54 LIVE-BUT-UNUSED
// (only H reads it later) while needing sp[9]+24 w-regs+temps (~95 > 64) —
// the allocator spills ~36 acc values around F+G. Fix: H reads h2 back from
// the f16 pair-slots F0 already wrote to LDS; acc dies at F0, F+G pressure
// drops to ~45. h2 is already consumed as f16 by E2/F+G, so precision class
// is unchanged. Everything else byte-identical to R12 (E2 packed dot2,
// GSCR=232, 4096x128).
constexpr int GSCR = 232;
constexpr int O_S  = 0;     // s[27] f32
constexpr int O_F1 = 28;    // f1[27] f32  (also holds obs[9] during phase B)
constexpr int O_F2 = 56;    // f2[3][10] f32
constexpr int O_U  = 88;    // h1 tile [9][32] f16 (576B) / att [27] x 5-dword rows (540B)
// h2 overlay lives at group base (floats 0..215): used only after s/f1/f2/att are dead.

#if defined(__has_builtin)
#  if __has_builtin(__builtin_amdgcn_fdot2)
#    define FDOT2(a,b,c) __builtin_amdgcn_fdot2((a),(b),(c),false)
#  endif
#  if __has_builtin(__builtin_amdgcn_cvt_pkrtz)
#    define PKH(a,b) ((v2h)__builtin_amdgcn_cvt_pkrtz((a),(b)))
#  endif
#endif
#ifndef FDOT2
__device__ __forceinline__ float fdot2_sw(v2h a, v2h b, float c) {
    return c + (float)a.x*(float)b.x + (float)a.y*(float)b.y;
}
#  define FDOT2(a,b,c) fdot2_sw((a),(b),(c))
#endif
#ifndef PKH
#  define PKH(a,b) ((v2h){(h16)(a), (h16)(b)})
#endif

union U4 { float4 f; v2h h[4]; };
union U1 { float  f; v2h h;    };

#define WAVE_SYNC() asm volatile("s_waitcnt lgkmcnt(0)" ::: "memory")

__device__ __forceinline__ float fast_rcp(float x) { return __builtin_amdgcn_rcpf(x); }
__device__ __forceinline__ float tanh_fast(float x) {
    float e = __expf(x + x);
    return 1.f - 2.f * fast_rcp(e + 1.f);
}

// ws layout (halves): [0,4608): w2H[c][i] (48x96)  [4608,5760): wp1P pair-slots:
//   wp1P[k][s] = { Wp1[c_lo][k], Wp1[c_hi][k] },  s=3*l8+kp, c_lo=l8+16*kp, c_hi=c_lo+8
__global__ void prep_kernel(const float* __restrict__ W2, const float* __restrict__ Wp1,
                            h16* __restrict__ ws) {
    int t = blockIdx.x * 256 + threadIdx.x;
    if (t < 48 * 96) {
        int c = t / 96, i = t - c * 96;
        int h = c >> 4, d = c & 15;
        ws[t] = (h16)W2[(h * 96 + i) * 16 + d];
    } else if (t < 48 * 96 + 576) {
        int t2 = t - 48 * 96;
        int k = t2 / 24, s = t2 - k * 24;
        int l = s / 3, kp = s - 3 * l;
        int clo = l + 16 * kp, chi = clo + 8;
        ws[4608 + 2 * t2]     = (h16)Wp1[clo * 24 + k];
        ws[4608 + 2 * t2 + 1] = (h16)Wp1[chi * 24 + k];
    }
}

__global__ __launch_bounds__(128, 4) void gnn_gat_kernel(
    const float* __restrict__ obs, const float* __restrict__ adj,
    const float* __restrict__ W1,  const float* __restrict__ a1,
    const float* __restrict__ a2,  const float* __restrict__ bp1,
    const float* __restrict__ Wp2, const h16* __restrict__ ws,
    float* __restrict__ out, int B)
{
    __shared__ float sW1[96];
    __shared__ float sC12[6];
    __shared__ unsigned sRb[9];     // per-row 9-bit adjacency masks
    __shared__ __align__(16) float smem[16 * GSCR];

    const int tid = threadIdx.x;
    if (tid < 96) sW1[tid] = W1[tid];
    if (tid < 9) {
        unsigned u = 0;
        for (int j = 0; j < 9; ++j)
            u |= (adj[tid * 9 + j] > 0.f ? 1u : 0u) << j;
        sRb[tid] = u;
    }
    if (tid < 6) {
        int gg = tid >> 1, w = tid & 1;
        float s = 0.f;
        for (int d = 0; d < 32; ++d)
            s += W1[gg * 32 + d] * a1[gg * 64 + w * 32 + d];
        sC12[tid] = s;
    }
    __syncthreads();

    const int wv = tid >> 6, lane = tid & 63;
    const int q = lane >> 3, l8 = lane & 7;
    float* g = smem + (wv * 8 + q) * GSCR;
    float4* hUf4 = (float4*)(g + O_U);            // h1 tile rows: 4 float4 each
    float4* h2f4 = (float4*)g;                    // h2 rows: 6 float4 each
    const float4* wsf4 = (const float4*)ws;

    const int slots = gridDim.x * 16;
    for (int b = (blockIdx.x * 2 + wv) * 8 + q; b < B; b += slots) {
        // ---- A: obs into registers (vectorized; static use only) + LDS copy ----
        float o_r[9];
        {
            const f4u* op = (const f4u*)(obs + (size_t)b * 9);
            f4u oa = op[0];
            f4u ob = op[1];
            float oc = obs[(size_t)b * 9 + 8];
            o_r[0] = oa.x; o_r[1] = oa.y; o_r[2] = oa.z; o_r[3] = oa.w;
            o_r[4] = ob.x; o_r[5] = ob.y; o_r[6] = ob.z; o_r[7] = ob.w;
            o_r[8] = oc;
        }
        g[O_F1 + l8] = obs[(size_t)b * 9 + l8];
        if (l8 == 0) g[O_F1 + 8] = obs[(size_t)b * 9 + 8];
        WAVE_SYNC();

        // ---- B: layer-1 collapsed attention -> s[g][n] in LDS ----
        #pragma unroll
        for (int it = 0; it < 4; ++it) {
            int t = l8 + 8 * it;
            if (t < 27) {
                int gg = (t >= 18) ? 2 : (t >= 9 ? 1 : 0);
                int n = t - 9 * gg;
                float f1 = sC12[2 * gg] * g[O_F1 + n];   // LDS lookups (runtime n, gg)
                float c2 = sC12[2 * gg + 1];
                unsigned rbits = sRb[n];
                float e[9], m = -3.0e38f;
                #pragma unroll
                for (int j = 0; j < 9; ++j) {
                    float x = f1 + c2 * o_r[j];
                    x = x > 0.f ? x : ALPHA * x;
                    x = ((rbits >> j) & 1) ? x : MASKV;
                    e[j] = x; m = fmaxf(m, x);
                }
                float sum = 0.f, sw = 0.f;
                #pragma unroll
                for (int j = 0; j < 9; ++j) {
                    float p = __expf(e[j] - m);
                    sum += p; sw += p * o_r[j];
                }
                g[O_S + t] = sw * fast_rcp(sum);
            }
        }
        WAVE_SYNC();

        // ---- C/D: 3 K-tiles of 32; h1 f16 in LDS, GEMM via v_dot2 ----
        float acc[9][6];
        #pragma unroll
        for (int n = 0; n < 9; ++n)
            #pragma unroll
            for (int k = 0; k < 6; ++k) acc[n][k] = 0.f;

        for (int p = 0; p < 3; ++p) {
            // C: h1[n][0..31] = elu(s[p][n] * W1[32p..32p+31]) as f16
            #pragma unroll
            for (int it = 0; it < 5; ++it) {
                int t = l8 + 8 * it;
                if (t < 36) {
                    int n = t >> 2, ib = t & 3;
                    int i0 = 32 * p + 8 * ib;
                    float sv = g[O_S + p * 9 + n];
                    float4 wa = *(const float4*)&sW1[i0];
                    float4 wb = *(const float4*)&sW1[i0 + 4];
                    float v0 = sv * wa.x, v1 = sv * wa.y, v2 = sv * wa.z, v3 = sv * wa.w;
                    float v4 = sv * wb.x, v5 = sv * wb.y, v6 = sv * wb.z, v7 = sv * wb.w;
                    v0 = v0 > 0.f ? v0 : __expf(v0) - 1.f;
                    v1 = v1 > 0.f ? v1 : __expf(v1) - 1.f;
                    v2 = v2 > 0.f ? v2 : __expf(v2) - 1.f;
                    v3 = v3 > 0.f ? v3 : __expf(v3) - 1.f;
                    v4 = v4 > 0.f ? v4 : __expf(v4) - 1.f;
                    v5 = v5 > 0.f ? v5 : __expf(v5) - 1.f;
                    v6 = v6 > 0.f ? v6 : __expf(v6) - 1.f;
                    v7 = v7 > 0.f ? v7 : __expf(v7) - 1.f;
                    U4 u;
                    u.h[0] = PKH(v0, v1);
                    u.h[1] = PKH(v2, v3);
                    u.h[2] = PKH(v4, v5);
                    u.h[3] = PKH(v6, v7);
                    hUf4[n * 4 + ib] = u.f;
                }
            }
            WAVE_SYNC();

            // D: acc[n][k] += h1[n][i:i+8] . w2[c][i:i+8]
            #pragma unroll
            for (int ib = 0; ib < 4; ++ib) {
                U4 w[6];
                #pragma unroll
                for (int k = 0; k < 6; ++k)
                    w[k].f = wsf4[(l8 + 8 * k) * 12 + p * 4 + ib];
                #pragma unroll
                for (int n = 0; n < 9; ++n) {
                    U4 hh; hh.f = hUf4[n * 4 + ib];
                    #pragma unroll
                    for (int k = 0; k < 6; ++k) {
                        float a = acc[n][k];
                        a = FDOT2(hh.h[0], w[k].h[0], a);
                        a = FDOT2(hh.h[1], w[k].h[1], a);
                        a = FDOT2(hh.h[2], w[k].h[2], a);
                        a = FDOT2(hh.h[3], w[k].h[3], a);
                        acc[n][k] = a;
                    }
                }
            }
            WAVE_SYNC();
        }

        // ---- f1/f2 for layer-2 attention (butterfly over 8 d-lanes) ----
        #pragma unroll
        for (int h = 0; h < 3; ++h) {
            float aa0 = a2[h * 32 + l8];
            float aa1 = a2[h * 32 + 8 + l8];
            float ab0 = a2[h * 32 + 16 + l8];
            float ab1 = a2[h * 32 + 24 + l8];
            #pragma unroll
            for (int n = 0; n < 9; ++n) {
                float v1 = acc[n][2 * h] * aa0 + acc[n][2 * h + 1] * aa1;
                float v2 = acc[n][2 * h] * ab0 + acc[n][2 * h + 1] * ab1;
                v1 += __shfl_xor(v1, 1, 8); v1 += __shfl_xor(v1, 2, 8); v1 += __shfl_xor(v1, 4, 8);
                v2 += __shfl_xor(v2, 1, 8); v2 += __shfl_xor(v2, 2, 8); v2 += __shfl_xor(v2, 4, 8);
                if (((h * 9 + n) & 7) == l8) {
                    g[O_F1 + h * 9 + n]  = v1;
                    g[O_F2 + h * 10 + n] = v2;
                }
            }
        }
        WAVE_SYNC();

        // ---- E1: att rows -> f16 LDS, packed 5 dwords per row (20 B stride) ----
        #pragma unroll
        for (int it = 0; it < 4; ++it) {
            int t = l8 + 8 * it;
            if (t < 27) {
                int h = (t >= 18) ? 2 : (t >= 9 ? 1 : 0);
                int i = t - 9 * h;
                float f1i = g[O_F1 + t];
                unsigned rbits = sRb[i];
                float e[9], m = -3.0e38f;
                #pragma unroll
                for (int j = 0; j < 9; ++j) {
                    float x = f1i + g[O_F2 + h * 10 + j];   // direct LDS read
                    x = x > 0.f ? x : ALPHA * x;
                    x = ((rbits >> j) & 1) ? x : MASKV;
                    e[j] = x; m = fmaxf(m, x);
                }
                float p[9], sum = 0.f;
                #pragma unroll
                for (int j = 0; j < 9; ++j) { p[j] = __expf(e[j] - m); sum += p[j]; }
                float r = fast_rcp(sum);
                float* row = g + O_U + t * 5;
                U1 u0, u1, u2, u3, u4;
                u0.h = PKH(p[0] * r, p[1] * r);
                u1.h = PKH(p[2] * r, p[3] * r);
                u2.h = PKH(p[4] * r, p[5] * r);
                u3.h = PKH(p[6] * r, p[7] * r);
                u4.h = PKH(p[8] * r, 0.f);
                row[0] = u0.f; row[1] = u1.f; row[2] = u2.f;
                row[3] = u3.f; row[4] = u4.f;
            }
        }
        WAVE_SYNC();

        // ---- E2: h2 = att @ Wh2 via packed dot2 (att rows are v2h pairs) ----
        #pragma unroll
        for (int h = 0; h < 3; ++h) {
            v2h ca0 = PKH(acc[0][2*h],   acc[1][2*h]);
            v2h ca1 = PKH(acc[2][2*h],   acc[3][2*h]);
            v2h ca2 = PKH(acc[4][2*h],   acc[5][2*h]);
            v2h ca3 = PKH(acc[6][2*h],   acc[7][2*h]);
            v2h ca4 = PKH(acc[8][2*h],   0.f);
            v2h cb0 = PKH(acc[0][2*h+1], acc[1][2*h+1]);
            v2h cb1 = PKH(acc[2][2*h+1], acc[3][2*h+1]);
            v2h cb2 = PKH(acc[4][2*h+1], acc[5][2*h+1]);
            v2h cb3 = PKH(acc[6][2*h+1], acc[7][2*h+1]);
            v2h cb4 = PKH(acc[8][2*h+1], 0.f);
            float t0[9], t1[9];
            #pragma unroll
            for (int i = 0; i < 9; ++i) {
                const float* row = g + O_U + (h * 9 + i) * 5;
                U1 r0, r1, r2, r3, r4;
                r0.f = row[0]; r1.f = row[1]; r2.f = row[2];
                r3.f = row[3]; r4.f = row[4];
                float s0 = 0.f, s1 = 0.f;
                s0 = FDOT2(r0.h, ca0, s0); s1 = FDOT2(r0.h, cb0, s1);
                s0 = FDOT2(r1.h, ca1, s0); s1 = FDOT2(r1.h, cb1, s1);
                s0 = FDOT2(r2.h, ca2, s0); s1 = FDOT2(r2.h, cb2, s1);
                s0 = FDOT2(r3.h, ca3, s0); s1 = FDOT2(r3.h, cb3, s1);
                s0 = FDOT2(r4.h, ca4, s0); s1 = FDOT2(r4.h, cb4, s1);
                t0[i] = s0; t1[i] = s1;
            }
            #pragma unroll
            for (int i = 0; i < 9; ++i) { acc[i][2 * h] = t0[i]; acc[i][2 * h + 1] = t1[i]; }
        }

        // ---- F0: pack h2 to f16 pair-slots in LDS (acc DIES here) ----
        #pragma unroll
        for (int n = 0; n < 9; ++n) {
            #pragma unroll
            for (int kp = 0; kp < 3; ++kp) {
                U1 u; u.h = PKH(acc[n][2 * kp], acc[n][2 * kp + 1]);
                ((float*)g)[n * 24 + 3 * l8 + kp] = u.f;
            }
        }
        WAVE_SYNC();

        // ---- F+G: scores via dot2 against pre-packed Wp1; butterfly once per n ----
        float sp[9];
        #pragma unroll
        for (int n = 0; n < 9; ++n) sp[n] = 0.f;
        #pragma unroll
        for (int kk = 0; kk < 3; ++kk) {
            int k = l8 + 8 * kk;
            float wqv = Wp2[k];
            float bqv = bp1[k];
            U4 w0, w1, w2u, w3, w4, w5;
            w0.f = wsf4[576 + k * 6 + 0];
            w1.f = wsf4[576 + k * 6 + 1];
            w2u.f = wsf4[576 + k * 6 + 2];
            w3.f = wsf4[576 + k * 6 + 3];
            w4.f = wsf4[576 + k * 6 + 4];
            w5.f = wsf4[576 + k * 6 + 5];
            #pragma unroll
            for (int n = 0; n < 9; ++n) {
                float a = 0.f;
                U4 x;
                x.f = h2f4[n * 6 + 0];
                a = FDOT2(x.h[0], w0.h[0], a); a = FDOT2(x.h[1], w0.h[1], a);
                a = FDOT2(x.h[2], w0.h[2], a); a = FDOT2(x.h[3], w0.h[3], a);
                x.f = h2f4[n * 6 + 1];
                a = FDOT2(x.h[0], w1.h[0], a); a = FDOT2(x.h[1], w1.h[1], a);
                a = FDOT2(x.h[2], w1.h[2], a); a = FDOT2(x.h[3], w1.h[3], a);
                x.f = h2f4[n * 6 + 2];
                a = FDOT2(x.h[0], w2u.h[0], a); a = FDOT2(x.h[1], w2u.h[1], a);
                a = FDOT2(x.h[2], w2u.h[2], a); a = FDOT2(x.h[3], w2u.h[3], a);
                x.f = h2f4[n * 6 + 3];
                a = FDOT2(x.h[0], w3.h[0], a); a = FDOT2(x.h[1], w3.h[1], a);
                a = FDOT2(x.h[2], w3.h[2], a); a = FDOT2(x.h[3], w3.h[3], a);
                x.f = h2f4[n * 6 + 4];
                a = FDOT2(x.h[0], w4.h[0], a); a = FDOT2(x.h[1], w4.h[1], a);
                a = FDOT2(x.h[2], w4.h[2], a); a = FDOT2(x.h[3], w4.h[3], a);
                x.f = h2f4[n * 6 + 5];
                a = FDOT2(x.h[0], w5.h[0], a); a = FDOT2(x.h[1], w5.h[1], a);
                a = FDOT2(x.h[2], w5.h[2], a); a = FDOT2(x.h[3], w5.h[3], a);
                float tv = tanh_fast(a + bqv);
                sp[n] += tv * wqv;
            }
        }
        #pragma unroll
        for (int n = 0; n < 9; ++n) {
            sp[n] += __shfl_xor(sp[n], 1, 8);
            sp[n] += __shfl_xor(sp[n], 2, 8);
            sp[n] += __shfl_xor(sp[n], 4, 8);
        }

        // ---- H: node softmax (bp2 cancels) + weighted sum ----
        // h2 read back from the F0 pair-slots (this lane's own writes) so acc
        // need not stay live across F+G — removes the ~36-dword spill set.
        float mx = sp[0];
        #pragma unroll
        for (int n = 1; n < 9; ++n) mx = fmaxf(mx, sp[n]);
        float wn9[9], sum = 0.f;
        #pragma unroll
        for (int n = 0; n < 9; ++n) { wn9[n] = __expf(sp[n] - mx); sum += wn9[n]; }
        float r = fast_rcp(sum);
        #pragma unroll
        for (int kp = 0; kp < 3; ++kp) {
            float ov0 = 0.f, ov1 = 0.f;
            #pragma unroll
            for (int n = 0; n < 9; ++n) {
                U1 u; u.f = ((float*)g)[n * 24 + 3 * l8 + kp];
                ov0 += (float)u.h.x * wn9[n];
                ov1 += (float)u.h.y * wn9[n];
            }
            out[(size_t)b * 48 + l8 + 16 * kp]     = ov0 * r;
            out[(size_t)b * 48 + l8 + 16 * kp + 8] = ov1 * r;
        }
        WAVE_SYNC();
    }
}

extern "C" void kernel_launch(void* const* d_in, const int* in_sizes, int n_in,
                              void* d_out, int out_size, void* d_ws, size_t ws_size,
                              hipStream_t stream) {
    const float* obs = (const float*)d_in[0];
    const float* adj = (const float*)d_in[1];
    const float* W1  = (const float*)d_in[2];
    const float* a1  = (const float*)d_in[3];
    const float* W2  = (const float*)d_in[4];
    const float* a2  = (const float*)d_in[5];
    const float* Wp1 = (const float*)d_in[6];
    const float* bp1 = (const float*)d_in[7];
    const float* Wp2 = (const float*)d_in[8];
    float* out = (float*)d_out;
    h16* ws = (h16*)d_ws;

    const int B = in_sizes[0] / 9;

    prep_kernel<<<(48 * 96 + 576 + 255) / 256, 256, 0, stream>>>(W2, Wp1, ws);

    gnn_gat_kernel<<<4096, 128, 0, stream>>>(
        obs, adj, W1, a1, a2, bp1, Wp2, ws, out, B);
}

// Round 14
// 457.578 us; speedup vs baseline: 1.3191x; 1.3191x over previous
//
#include <hip/hip_runtime.h>
#include <math.h>

typedef _Float16 h16;
typedef _Float16 v2h __attribute__((ext_vector_type(2)));
typedef float f4u __attribute__((ext_vector_type(4), aligned(4)));

#define ALPHA 0.2f
#define MASKV -9000000000000000.0f

// v14 = R12 (284us steady best: E2 packed dot2, GSCR=232, H reads acc from
// registers) with the grid-stride b-loop ELIMINATED: grid 8192 x 128, each
// 8-lane group handles exactly ONE graph (8192*16 = 131072 = B, no tail).
// Rationale: each wave ran exactly 2 loop iterations; the loop forces b,
// slots, and base addressing live across all 12 phases and shapes regalloc.
// Straight-line code frees the allocator (rematerialization, no backedge).
// Tests the last untested spill hypothesis (loop-carried state); if traffic
// is unchanged, R12's structure is confirmed final.
// R13's acc-liveness change is REVERTED (it quadrupled traffic: the
// allocator spilled more, not less - liveness surgery is chaotic here).
constexpr int GSCR = 232;
constexpr int O_S  = 0;     // s[27] f32
constexpr int O_F1 = 28;    // f1[27] f32  (also holds obs[9] during phase B)
constexpr int O_F2 = 56;    // f2[3][10] f32
constexpr int O_U  = 88;    // h1 tile [9][32] f16 (576B) / att [27] x 5-dword rows (540B)
// h2 overlay lives at group base (floats 0..215): used only after s/f1/f2/att are dead.

#if defined(__has_builtin)
#  if __has_builtin(__builtin_amdgcn_fdot2)
#    define FDOT2(a,b,c) __builtin_amdgcn_fdot2((a),(b),(c),false)
#  endif
#  if __has_builtin(__builtin_amdgcn_cvt_pkrtz)
#    define PKH(a,b) ((v2h)__builtin_amdgcn_cvt_pkrtz((a),(b)))
#  endif
#endif
#ifndef FDOT2
__device__ __forceinline__ float fdot2_sw(v2h a, v2h b, float c) {
    return c + (float)a.x*(float)b.x + (float)a.y*(float)b.y;
}
#  define FDOT2(a,b,c) fdot2_sw((a),(b),(c))
#endif
#ifndef PKH
#  define PKH(a,b) ((v2h){(h16)(a), (h16)(b)})
#endif

union U4 { float4 f; v2h h[4]; };
union U1 { float  f; v2h h;    };

#define WAVE_SYNC() asm volatile("s_waitcnt lgkmcnt(0)" ::: "memory")

__device__ __forceinline__ float fast_rcp(float x) { return __builtin_amdgcn_rcpf(x); }
__device__ __forceinline__ float tanh_fast(float x) {
    float e = __expf(x + x);
    return 1.f - 2.f * fast_rcp(e + 1.f);
}

// ws layout (halves): [0,4608): w2H[c][i] (48x96)  [4608,5760): wp1P pair-slots:
//   wp1P[k][s] = { Wp1[c_lo][k], Wp1[c_hi][k] },  s=3*l8+kp, c_lo=l8+16*kp, c_hi=c_lo+8
__global__ void prep_kernel(const float* __restrict__ W2, const float* __restrict__ Wp1,
                            h16* __restrict__ ws) {
    int t = blockIdx.x * 256 + threadIdx.x;
    if (t < 48 * 96) {
        int c = t / 96, i = t - c * 96;
        int h = c >> 4, d = c & 15;
        ws[t] = (h16)W2[(h * 96 + i) * 16 + d];
    } else if (t < 48 * 96 + 576) {
        int t2 = t - 48 * 96;
        int k = t2 / 24, s = t2 - k * 24;
        int l = s / 3, kp = s - 3 * l;
        int clo = l + 16 * kp, chi = clo + 8;
        ws[4608 + 2 * t2]     = (h16)Wp1[clo * 24 + k];
        ws[4608 + 2 * t2 + 1] = (h16)Wp1[chi * 24 + k];
    }
}

__global__ __launch_bounds__(128, 4) void gnn_gat_kernel(
    const float* __restrict__ obs, const float* __restrict__ adj,
    const float* __restrict__ W1,  const float* __restrict__ a1,
    const float* __restrict__ a2,  const float* __restrict__ bp1,
    const float* __restrict__ Wp2, const h16* __restrict__ ws,
    float* __restrict__ out, int B)
{
    __shared__ float sW1[96];
    __shared__ float sC12[6];
    __shared__ unsigned sRb[9];     // per-row 9-bit adjacency masks
    __shared__ __align__(16) float smem[16 * GSCR];

    const int tid = threadIdx.x;
    if (tid < 96) sW1[tid] = W1[tid];
    if (tid < 9) {
        unsigned u = 0;
        for (int j = 0; j < 9; ++j)
            u |= (adj[tid * 9 + j] > 0.f ? 1u : 0u) << j;
        sRb[tid] = u;
    }
    if (tid < 6) {
        int gg = tid >> 1, w = tid & 1;
        float s = 0.f;
        for (int d = 0; d < 32; ++d)
            s += W1[gg * 32 + d] * a1[gg * 64 + w * 32 + d];
        sC12[tid] = s;
    }
    __syncthreads();

    const int wv = tid >> 6, lane = tid & 63;
    const int q = lane >> 3, l8 = lane & 7;
    float* g = smem + (wv * 8 + q) * GSCR;
    float4* hUf4 = (float4*)(g + O_U);            // h1 tile rows: 4 float4 each
    float4* h2f4 = (float4*)g;                    // h2 rows: 6 float4 each
    const float4* wsf4 = (const float4*)ws;

    const int b = (blockIdx.x * 2 + wv) * 8 + q;  // ONE graph per group
    if (b < B) {
        // ---- A: obs into registers (vectorized; static use only) + LDS copy ----
        float o_r[9];
        {
            const f4u* op = (const f4u*)(obs + (size_t)b * 9);
            f4u oa = op[0];
            f4u ob = op[1];
            float oc = obs[(size_t)b * 9 + 8];
            o_r[0] = oa.x; o_r[1] = oa.y; o_r[2] = oa.z; o_r[3] = oa.w;
            o_r[4] = ob.x; o_r[5] = ob.y; o_r[6] = ob.z; o_r[7] = ob.w;
            o_r[8] = oc;
        }
        g[O_F1 + l8] = obs[(size_t)b * 9 + l8];
        if (l8 == 0) g[O_F1 + 8] = obs[(size_t)b * 9 + 8];
        WAVE_SYNC();

        // ---- B: layer-1 collapsed attention -> s[g][n] in LDS ----
        #pragma unroll
        for (int it = 0; it < 4; ++it) {
            int t = l8 + 8 * it;
            if (t < 27) {
                int gg = (t >= 18) ? 2 : (t >= 9 ? 1 : 0);
                int n = t - 9 * gg;
                float f1 = sC12[2 * gg] * g[O_F1 + n];   // LDS lookups (runtime n, gg)
                float c2 = sC12[2 * gg + 1];
                unsigned rbits = sRb[n];
                float e[9], m = -3.0e38f;
                #pragma unroll
                for (int j = 0; j < 9; ++j) {
                    float x = f1 + c2 * o_r[j];
                    x = x > 0.f ? x : ALPHA * x;
                    x = ((rbits >> j) & 1) ? x : MASKV;
                    e[j] = x; m = fmaxf(m, x);
                }
                float sum = 0.f, sw = 0.f;
                #pragma unroll
                for (int j = 0; j < 9; ++j) {
                    float p = __expf(e[j] - m);
                    sum += p; sw += p * o_r[j];
                }
                g[O_S + t] = sw * fast_rcp(sum);
            }
        }
        WAVE_SYNC();

        // ---- C/D: 3 K-tiles of 32; h1 f16 in LDS, GEMM via v_dot2 ----
        float acc[9][6];
        #pragma unroll
        for (int n = 0; n < 9; ++n)
            #pragma unroll
            for (int k = 0; k < 6; ++k) acc[n][k] = 0.f;

        for (int p = 0; p < 3; ++p) {
            // C: h1[n][0..31] = elu(s[p][n] * W1[32p..32p+31]) as f16
            #pragma unroll
            for (int it = 0; it < 5; ++it) {
                int t = l8 + 8 * it;
                if (t < 36) {
                    int n = t >> 2, ib = t & 3;
                    int i0 = 32 * p + 8 * ib;
                    float sv = g[O_S + p * 9 + n];
                    float4 wa = *(const float4*)&sW1[i0];
                    float4 wb = *(const float4*)&sW1[i0 + 4];
                    float v0 = sv * wa.x, v1 = sv * wa.y, v2 = sv * wa.z, v3 = sv * wa.w;
                    float v4 = sv * wb.x, v5 = sv * wb.y, v6 = sv * wb.z, v7 = sv * wb.w;
                    v0 = v0 > 0.f ? v0 : __expf(v0) - 1.f;
                    v1 = v1 > 0.f ? v1 : __expf(v1) - 1.f;
                    v2 = v2 > 0.f ? v2 : __expf(v2) - 1.f;
                    v3 = v3 > 0.f ? v3 : __expf(v3) - 1.f;
                    v4 = v4 > 0.f ? v4 : __expf(v4) - 1.f;
                    v5 = v5 > 0.f ? v5 : __expf(v5) - 1.f;
                    v6 = v6 > 0.f ? v6 : __expf(v6) - 1.f;
                    v7 = v7 > 0.f ? v7 : __expf(v7) - 1.f;
                    U4 u;
                    u.h[0] = PKH(v0, v1);
                    u.h[1] = PKH(v2, v3);
                    u.h[2] = PKH(v4, v5);
                    u.h[3] = PKH(v6, v7);
                    hUf4[n * 4 + ib] = u.f;
                }
            }
            WAVE_SYNC();

            // D: acc[n][k] += h1[n][i:i+8] . w2[c][i:i+8]
            #pragma unroll
            for (int ib = 0; ib < 4; ++ib) {
                U4 w[6];
                #pragma unroll
                for (int k = 0; k < 6; ++k)
                    w[k].f = wsf4[(l8 + 8 * k) * 12 + p * 4 + ib];
                #pragma unroll
                for (int n = 0; n < 9; ++n) {
                    U4 hh; hh.f = hUf4[n * 4 + ib];
                    #pragma unroll
                    for (int k = 0; k < 6; ++k) {
                        float a = acc[n][k];
                        a = FDOT2(hh.h[0], w[k].h[0], a);
                        a = FDOT2(hh.h[1], w[k].h[1], a);
                        a = FDOT2(hh.h[2], w[k].h[2], a);
                        a = FDOT2(hh.h[3], w[k].h[3], a);
                        acc[n][k] = a;
                    }
                }
            }
            WAVE_SYNC();
        }

        // ---- f1/f2 for layer-2 attention (butterfly over 8 d-lanes) ----
        #pragma unroll
        for (int h = 0; h < 3; ++h) {
            float aa0 = a2[h * 32 + l8];
            float aa1 = a2[h * 32 + 8 + l8];
            float ab0 = a2[h * 32 + 16 + l8];
            float ab1 = a2[h * 32 + 24 + l8];
            #pragma unroll
            for (int n = 0; n < 9; ++n) {
                float v1 = acc[n][2 * h] * aa0 + acc[n][2 * h + 1] * aa1;
                float v2 = acc[n][2 * h] * ab0 + acc[n][2 * h + 1] * ab1;
                v1 += __shfl_xor(v1, 1, 8); v1 += __shfl_xor(v1, 2, 8); v1 += __shfl_xor(v1, 4, 8);
                v2 += __shfl_xor(v2, 1, 8); v2 += __shfl_xor(v2, 2, 8); v2 += __shfl_xor(v2, 4, 8);
                if (((h * 9 + n) & 7) == l8) {
                    g[O_F1 + h * 9 + n]  = v1;
                    g[O_F2 + h * 10 + n] = v2;
                }
            }
        }
        WAVE_SYNC();

        // ---- E1: att rows -> f16 LDS, packed 5 dwords per row (20 B stride) ----
        #pragma unroll
        for (int it = 0; it < 4; ++it) {
            int t = l8 + 8 * it;
            if (t < 27) {
                int h = (t >= 18) ? 2 : (t >= 9 ? 1 : 0);
                int i = t - 9 * h;
                float f1i = g[O_F1 + t];
                unsigned rbits = sRb[i];
                float e[9], m = -3.0e38f;
                #pragma unroll
                for (int j = 0; j < 9; ++j) {
                    float x = f1i + g[O_F2 + h * 10 + j];   // direct LDS read
                    x = x > 0.f ? x : ALPHA * x;
                    x = ((rbits >> j) & 1) ? x : MASKV;
                    e[j] = x; m = fmaxf(m, x);
                }
                float p[9], sum = 0.f;
                #pragma unroll
                for (int j = 0; j < 9; ++j) { p[j] = __expf(e[j] - m); sum += p[j]; }
                float r = fast_rcp(sum);
                float* row = g + O_U + t * 5;
                U1 u0, u1, u2, u3, u4;
                u0.h = PKH(p[0] * r, p[1] * r);
                u1.h = PKH(p[2] * r, p[3] * r);
                u2.h = PKH(p[4] * r, p[5] * r);
                u3.h = PKH(p[6] * r, p[7] * r);
                u4.h = PKH(p[8] * r, 0.f);
                row[0] = u0.f; row[1] = u1.f; row[2] = u2.f;
                row[3] = u3.f; row[4] = u4.f;
            }
        }
        WAVE_SYNC();

        // ---- E2: h2 = att @ Wh2 via packed dot2 (att rows are v2h pairs) ----
        #pragma unroll
        for (int h = 0; h < 3; ++h) {
            v2h ca0 = PKH(acc[0][2*h],   acc[1][2*h]);
            v2h ca1 = PKH(acc[2][2*h],   acc[3][2*h]);
            v2h ca2 = PKH(acc[4][2*h],   acc[5][2*h]);
            v2h ca3 = PKH(acc[6][2*h],   acc[7][2*h]);
            v2h ca4 = PKH(acc[8][2*h],   0.f);
            v2h cb0 = PKH(acc[0][2*h+1], acc[1][2*h+1]);
            v2h cb1 = PKH(acc[2][2*h+1], acc[3][2*h+1]);
            v2h cb2 = PKH(acc[4][2*h+1], acc[5][2*h+1]);
            v2h cb3 = PKH(acc[6][2*h+1], acc[7][2*h+1]);
            v2h cb4 = PKH(acc[8][2*h+1], 0.f);
            float t0[9], t1[9];
            #pragma unroll
            for (int i = 0; i < 9; ++i) {
                const float* row = g + O_U + (h * 9 + i) * 5;
                U1 r0, r1, r2, r3, r4;
                r0.f = row[0]; r1.f = row[1]; r2.f = row[2];
                r3.f = row[3]; r4.f = row[4];
                float s0 = 0.f, s1 = 0.f;
                s0 = FDOT2(r0.h, ca0, s0); s1 = FDOT2(r0.h, cb0, s1);
                s0 = FDOT2(r1.h, ca1, s0); s1 = FDOT2(r1.h, cb1, s1);
                s0 = FDOT2(r2.h, ca2, s0); s1 = FDOT2(r2.h, cb2, s1);
                s0 = FDOT2(r3.h, ca3, s0); s1 = FDOT2(r3.h, cb3, s1);
                s0 = FDOT2(r4.h, ca4, s0); s1 = FDOT2(r4.h, cb4, s1);
                t0[i] = s0; t1[i] = s1;
            }
            #pragma unroll
            for (int i = 0; i < 9; ++i) { acc[i][2 * h] = t0[i]; acc[i][2 * h + 1] = t1[i]; }
        }

        // ---- F0: pack h2 to f16 pair-slots in LDS (overlay at group base) ----
        #pragma unroll
        for (int n = 0; n < 9; ++n) {
            #pragma unroll
            for (int kp = 0; kp < 3; ++kp) {
                U1 u; u.h = PKH(acc[n][2 * kp], acc[n][2 * kp + 1]);
                ((float*)g)[n * 24 + 3 * l8 + kp] = u.f;
            }
        }
        WAVE_SYNC();

        // ---- F+G: scores via dot2 against pre-packed Wp1; butterfly once per n ----
        float sp[9];
        #pragma unroll
        for (int n = 0; n < 9; ++n) sp[n] = 0.f;
        #pragma unroll
        for (int kk = 0; kk < 3; ++kk) {
            int k = l8 + 8 * kk;
            float wqv = Wp2[k];
            float bqv = bp1[k];
            U4 w0, w1, w2u, w3, w4, w5;
            w0.f = wsf4[576 + k * 6 + 0];
            w1.f = wsf4[576 + k * 6 + 1];
            w2u.f = wsf4[576 + k * 6 + 2];
            w3.f = wsf4[576 + k * 6 + 3];
            w4.f = wsf4[576 + k * 6 + 4];
            w5.f = wsf4[576 + k * 6 + 5];
            #pragma unroll
            for (int n = 0; n < 9; ++n) {
                float a = 0.f;
                U4 x;
                x.f = h2f4[n * 6 + 0];
                a = FDOT2(x.h[0], w0.h[0], a); a = FDOT2(x.h[1], w0.h[1], a);
                a = FDOT2(x.h[2], w0.h[2], a); a = FDOT2(x.h[3], w0.h[3], a);
                x.f = h2f4[n * 6 + 1];
                a = FDOT2(x.h[0], w1.h[0], a); a = FDOT2(x.h[1], w1.h[1], a);
                a = FDOT2(x.h[2], w1.h[2], a); a = FDOT2(x.h[3], w1.h[3], a);
                x.f = h2f4[n * 6 + 2];
                a = FDOT2(x.h[0], w2u.h[0], a); a = FDOT2(x.h[1], w2u.h[1], a);
                a = FDOT2(x.h[2], w2u.h[2], a); a = FDOT2(x.h[3], w2u.h[3], a);
                x.f = h2f4[n * 6 + 3];
                a = FDOT2(x.h[0], w3.h[0], a); a = FDOT2(x.h[1], w3.h[1], a);
                a = FDOT2(x.h[2], w3.h[2], a); a = FDOT2(x.h[3], w3.h[3], a);
                x.f = h2f4[n * 6 + 4];
                a = FDOT2(x.h[0], w4.h[0], a); a = FDOT2(x.h[1], w4.h[1], a);
                a = FDOT2(x.h[2], w4.h[2], a); a = FDOT2(x.h[3], w4.h[3], a);
                x.f = h2f4[n * 6 + 5];
                a = FDOT2(x.h[0], w5.h[0], a); a = FDOT2(x.h[1], w5.h[1], a);
                a = FDOT2(x.h[2], w5.h[2], a); a = FDOT2(x.h[3], w5.h[3], a);
                float tv = tanh_fast(a + bqv);
                sp[n] += tv * wqv;
            }
        }
        #pragma unroll
        for (int n = 0; n < 9; ++n) {
            sp[n] += __shfl_xor(sp[n], 1, 8);
            sp[n] += __shfl_xor(sp[n], 2, 8);
            sp[n] += __shfl_xor(sp[n], 4, 8);
        }

        // ---- H: node softmax (bp2 cancels) + weighted sum -> out ----
        float mx = sp[0];
        #pragma unroll
        for (int n = 1; n < 9; ++n) mx = fmaxf(mx, sp[n]);
        float wn9[9], sum = 0.f;
        #pragma unroll
        for (int n = 0; n < 9; ++n) { wn9[n] = __expf(sp[n] - mx); sum += wn9[n]; }
        float r = fast_rcp(sum);
        #pragma unroll
        for (int k = 0; k < 6; ++k) {
            float ov = 0.f;
            #pragma unroll
            for (int n = 0; n < 9; ++n) ov += wn9[n] * acc[n][k];
            out[(size_t)b * 48 + l8 + 8 * k] = ov * r;
        }
    }
}

extern "C" void kernel_launch(void* const* d_in, const int* in_sizes, int n_in,
                              void* d_out, int out_size, void* d_ws, size_t ws_size,
                              hipStream_t stream) {
    const float* obs = (const float*)d_in[0];
    const float* adj = (const float*)d_in[1];
    const float* W1  = (const float*)d_in[2];
    const float* a1  = (const float*)d_in[3];
    const float* W2  = (const float*)d_in[4];
    const float* a2  = (const float*)d_in[5];
    const float* Wp1 = (const float*)d_in[6];
    const float* bp1 = (const float*)d_in[7];
    const float* Wp2 = (const float*)d_in[8];
    float* out = (float*)d_out;
    h16* ws = (h16*)d_ws;

    const int B = in_sizes[0] / 9;
    const int nblk = (B + 15) / 16;   // one graph per 8-lane group

    prep_kernel<<<(48 * 96 + 576 + 255) / 256, 256, 0, stream>>>(W2, Wp1, ws);

    gnn_gat_kernel<<<nblk, 128, 0, stream>>>(
        obs, adj, W1, a1, a2, bp1, Wp2, ws, out, B);
}

// Round 15
// 333.183 us; speedup vs baseline: 1.8117x; 1.3734x over previous
//
#include <hip/hip_runtime.h>
#include <math.h>

typedef _Float16 h16;
typedef _Float16 v2h __attribute__((ext_vector_type(2)));
typedef float f4u __attribute__((ext_vector_type(4), aligned(4)));

#define ALPHA 0.2f
#define MASKV -9000000000000000.0f

// v15 = R12 verbatim (284us steady best). Session conclusion: four
// consecutive spill-surgery experiments all regressed (R10 128-reg budget:
// 5x traffic; R11 16-lane small-live-set: 10x; R13 acc-liveness-kill: 4x;
// R14 loop-removal: 3x) — the allocator/scheduler response to source
// perturbation is chaotic and R12 is the measured minimum of the surface.
// Structure: 8-lane groups, GSCR=232 conflict-free LDS layout, E2 as packed
// dot2 (acc pre-packed to v2h via cvt_pkrtz), vectorized obs load,
// 4096x128 grid with 2-trip grid-stride loop.
constexpr int GSCR = 232;
constexpr int O_S  = 0;     // s[27] f32
constexpr int O_F1 = 28;    // f1[27] f32  (also holds obs[9] during phase B)
constexpr int O_F2 = 56;    // f2[3][10] f32
constexpr int O_U  = 88;    // h1 tile [9][32] f16 (576B) / att [27] x 5-dword rows (540B)
// h2 overlay lives at group base (floats 0..215): used only after s/f1/f2/att are dead.

#if defined(__has_builtin)
#  if __has_builtin(__builtin_amdgcn_fdot2)
#    define FDOT2(a,b,c) __builtin_amdgcn_fdot2((a),(b),(c),false)
#  endif
#  if __has_builtin(__builtin_amdgcn_cvt_pkrtz)
#    define PKH(a,b) ((v2h)__builtin_amdgcn_cvt_pkrtz((a),(b)))
#  endif
#endif
#ifndef FDOT2
__device__ __forceinline__ float fdot2_sw(v2h a, v2h b, float c) {
    return c + (float)a.x*(float)b.x + (float)a.y*(float)b.y;
}
#  define FDOT2(a,b,c) fdot2_sw((a),(b),(c))
#endif
#ifndef PKH
#  define PKH(a,b) ((v2h){(h16)(a), (h16)(b)})
#endif

union U4 { float4 f; v2h h[4]; };
union U1 { float  f; v2h h;    };

#define WAVE_SYNC() asm volatile("s_waitcnt lgkmcnt(0)" ::: "memory")

__device__ __forceinline__ float fast_rcp(float x) { return __builtin_amdgcn_rcpf(x); }
__device__ __forceinline__ float tanh_fast(float x) {
    float e = __expf(x + x);
    return 1.f - 2.f * fast_rcp(e + 1.f);
}

// ws layout (halves): [0,4608): w2H[c][i] (48x96)  [4608,5760): wp1P pair-slots:
//   wp1P[k][s] = { Wp1[c_lo][k], Wp1[c_hi][k] },  s=3*l8+kp, c_lo=l8+16*kp, c_hi=c_lo+8
__global__ void prep_kernel(const float* __restrict__ W2, const float* __restrict__ Wp1,
                            h16* __restrict__ ws) {
    int t = blockIdx.x * 256 + threadIdx.x;
    if (t < 48 * 96) {
        int c = t / 96, i = t - c * 96;
        int h = c >> 4, d = c & 15;
        ws[t] = (h16)W2[(h * 96 + i) * 16 + d];
    } else if (t < 48 * 96 + 576) {
        int t2 = t - 48 * 96;
        int k = t2 / 24, s = t2 - k * 24;
        int l = s / 3, kp = s - 3 * l;
        int clo = l + 16 * kp, chi = clo + 8;
        ws[4608 + 2 * t2]     = (h16)Wp1[clo * 24 + k];
        ws[4608 + 2 * t2 + 1] = (h16)Wp1[chi * 24 + k];
    }
}

__global__ __launch_bounds__(128, 4) void gnn_gat_kernel(
    const float* __restrict__ obs, const float* __restrict__ adj,
    const float* __restrict__ W1,  const float* __restrict__ a1,
    const float* __restrict__ a2,  const float* __restrict__ bp1,
    const float* __restrict__ Wp2, const h16* __restrict__ ws,
    float* __restrict__ out, int B)
{
    __shared__ float sW1[96];
    __shared__ float sC12[6];
    __shared__ unsigned sRb[9];     // per-row 9-bit adjacency masks
    __shared__ __align__(16) float smem[16 * GSCR];

    const int tid = threadIdx.x;
    if (tid < 96) sW1[tid] = W1[tid];
    if (tid < 9) {
        unsigned u = 0;
        for (int j = 0; j < 9; ++j)
            u |= (adj[tid * 9 + j] > 0.f ? 1u : 0u) << j;
        sRb[tid] = u;
    }
    if (tid < 6) {
        int gg = tid >> 1, w = tid & 1;
        float s = 0.f;
        for (int d = 0; d < 32; ++d)
            s += W1[gg * 32 + d] * a1[gg * 64 + w * 32 + d];
        sC12[tid] = s;
    }
    __syncthreads();

    const int wv = tid >> 6, lane = tid & 63;
    const int q = lane >> 3, l8 = lane & 7;
    float* g = smem + (wv * 8 + q) * GSCR;
    float4* hUf4 = (float4*)(g + O_U);            // h1 tile rows: 4 float4 each
    float4* h2f4 = (float4*)g;                    // h2 rows: 6 float4 each
    const float4* wsf4 = (const float4*)ws;

    const int slots = gridDim.x * 16;
    for (int b = (blockIdx.x * 2 + wv) * 8 + q; b < B; b += slots) {
        // ---- A: obs into registers (vectorized; static use only) + LDS copy ----
        float o_r[9];
        {
            const f4u* op = (const f4u*)(obs + (size_t)b * 9);
            f4u oa = op[0];
            f4u ob = op[1];
            float oc = obs[(size_t)b * 9 + 8];
            o_r[0] = oa.x; o_r[1] = oa.y; o_r[2] = oa.z; o_r[3] = oa.w;
            o_r[4] = ob.x; o_r[5] = ob.y; o_r[6] = ob.z; o_r[7] = ob.w;
            o_r[8] = oc;
        }
        g[O_F1 + l8] = obs[(size_t)b * 9 + l8];
        if (l8 == 0) g[O_F1 + 8] = obs[(size_t)b * 9 + 8];
        WAVE_SYNC();

        // ---- B: layer-1 collapsed attention -> s[g][n] in LDS ----
        #pragma unroll
        for (int it = 0; it < 4; ++it) {
            int t = l8 + 8 * it;
            if (t < 27) {
                int gg = (t >= 18) ? 2 : (t >= 9 ? 1 : 0);
                int n = t - 9 * gg;
                float f1 = sC12[2 * gg] * g[O_F1 + n];   // LDS lookups (runtime n, gg)
                float c2 = sC12[2 * gg + 1];
                unsigned rbits = sRb[n];
                float e[9], m = -3.0e38f;
                #pragma unroll
                for (int j = 0; j < 9; ++j) {
                    float x = f1 + c2 * o_r[j];
                    x = x > 0.f ? x : ALPHA * x;
                    x = ((rbits >> j) & 1) ? x : MASKV;
                    e[j] = x; m = fmaxf(m, x);
                }
                float sum = 0.f, sw = 0.f;
                #pragma unroll
                for (int j = 0; j < 9; ++j) {
                    float p = __expf(e[j] - m);
                    sum += p; sw += p * o_r[j];
                }
                g[O_S + t] = sw * fast_rcp(sum);
            }
        }
        WAVE_SYNC();

        // ---- C/D: 3 K-tiles of 32; h1 f16 in LDS, GEMM via v_dot2 ----
        float acc[9][6];
        #pragma unroll
        for (int n = 0; n < 9; ++n)
            #pragma unroll
            for (int k = 0; k < 6; ++k) acc[n][k] = 0.f;

        for (int p = 0; p < 3; ++p) {
            // C: h1[n][0..31] = elu(s[p][n] * W1[32p..32p+31]) as f16
            #pragma unroll
            for (int it = 0; it < 5; ++it) {
                int t = l8 + 8 * it;
                if (t < 36) {
                    int n = t >> 2, ib = t & 3;
                    int i0 = 32 * p + 8 * ib;
                    float sv = g[O_S + p * 9 + n];
                    float4 wa = *(const float4*)&sW1[i0];
                    float4 wb = *(const float4*)&sW1[i0 + 4];
                    float v0 = sv * wa.x, v1 = sv * wa.y, v2 = sv * wa.z, v3 = sv * wa.w;
                    float v4 = sv * wb.x, v5 = sv * wb.y, v6 = sv * wb.z, v7 = sv * wb.w;
                    v0 = v0 > 0.f ? v0 : __expf(v0) - 1.f;
                    v1 = v1 > 0.f ? v1 : __expf(v1) - 1.f;
                    v2 = v2 > 0.f ? v2 : __expf(v2) - 1.f;
                    v3 = v3 > 0.f ? v3 : __expf(v3) - 1.f;
                    v4 = v4 > 0.f ? v4 : __expf(v4) - 1.f;
                    v5 = v5 > 0.f ? v5 : __expf(v5) - 1.f;
                    v6 = v6 > 0.f ? v6 : __expf(v6) - 1.f;
                    v7 = v7 > 0.f ? v7 : __expf(v7) - 1.f;
                    U4 u;
                    u.h[0] = PKH(v0, v1);
                    u.h[1] = PKH(v2, v3);
                    u.h[2] = PKH(v4, v5);
                    u.h[3] = PKH(v6, v7);
                    hUf4[n * 4 + ib] = u.f;
                }
            }
            WAVE_SYNC();

            // D: acc[n][k] += h1[n][i:i+8] . w2[c][i:i+8]
            #pragma unroll
            for (int ib = 0; ib < 4; ++ib) {
                U4 w[6];
                #pragma unroll
                for (int k = 0; k < 6; ++k)
                    w[k].f = wsf4[(l8 + 8 * k) * 12 + p * 4 + ib];
                #pragma unroll
                for (int n = 0; n < 9; ++n) {
                    U4 hh; hh.f = hUf4[n * 4 + ib];
                    #pragma unroll
                    for (int k = 0; k < 6; ++k) {
                        float a = acc[n][k];
                        a = FDOT2(hh.h[0], w[k].h[0], a);
                        a = FDOT2(hh.h[1], w[k].h[1], a);
                        a = FDOT2(hh.h[2], w[k].h[2], a);
                        a = FDOT2(hh.h[3], w[k].h[3], a);
                        acc[n][k] = a;
                    }
                }
            }
            WAVE_SYNC();
        }

        // ---- f1/f2 for layer-2 attention (butterfly over 8 d-lanes) ----
        #pragma unroll
        for (int h = 0; h < 3; ++h) {
            float aa0 = a2[h * 32 + l8];
            float aa1 = a2[h * 32 + 8 + l8];
            float ab0 = a2[h * 32 + 16 + l8];
            float ab1 = a2[h * 32 + 24 + l8];
            #pragma unroll
            for (int n = 0; n < 9; ++n) {
                float v1 = acc[n][2 * h] * aa0 + acc[n][2 * h + 1] * aa1;
                float v2 = acc[n][2 * h] * ab0 + acc[n][2 * h + 1] * ab1;
                v1 += __shfl_xor(v1, 1, 8); v1 += __shfl_xor(v1, 2, 8); v1 += __shfl_xor(v1, 4, 8);
                v2 += __shfl_xor(v2, 1, 8); v2 += __shfl_xor(v2, 2, 8); v2 += __shfl_xor(v2, 4, 8);
                if (((h * 9 + n) & 7) == l8) {
                    g[O_F1 + h * 9 + n]  = v1;
                    g[O_F2 + h * 10 + n] = v2;
                }
            }
        }
        WAVE_SYNC();

        // ---- E1: att rows -> f16 LDS, packed 5 dwords per row (20 B stride) ----
        #pragma unroll
        for (int it = 0; it < 4; ++it) {
            int t = l8 + 8 * it;
            if (t < 27) {
                int h = (t >= 18) ? 2 : (t >= 9 ? 1 : 0);
                int i = t - 9 * h;
                float f1i = g[O_F1 + t];
                unsigned rbits = sRb[i];
                float e[9], m = -3.0e38f;
                #pragma unroll
                for (int j = 0; j < 9; ++j) {
                    float x = f1i + g[O_F2 + h * 10 + j];   // direct LDS read
                    x = x > 0.f ? x : ALPHA * x;
                    x = ((rbits >> j) & 1) ? x : MASKV;
                    e[j] = x; m = fmaxf(m, x);
                }
                float p[9], sum = 0.f;
                #pragma unroll
                for (int j = 0; j < 9; ++j) { p[j] = __expf(e[j] - m); sum += p[j]; }
                float r = fast_rcp(sum);
                float* row = g + O_U + t * 5;
                U1 u0, u1, u2, u3, u4;
                u0.h = PKH(p[0] * r, p[1] * r);
                u1.h = PKH(p[2] * r, p[3] * r);
                u2.h = PKH(p[4] * r, p[5] * r);
                u3.h = PKH(p[6] * r, p[7] * r);
                u4.h = PKH(p[8] * r, 0.f);
                row[0] = u0.f; row[1] = u1.f; row[2] = u2.f;
                row[3] = u3.f; row[4] = u4.f;
            }
        }
        WAVE_SYNC();

        // ---- E2: h2 = att @ Wh2 via packed dot2 (att rows are v2h pairs) ----
        #pragma unroll
        for (int h = 0; h < 3; ++h) {
            v2h ca0 = PKH(acc[0][2*h],   acc[1][2*h]);
            v2h ca1 = PKH(acc[2][2*h],   acc[3][2*h]);
            v2h ca2 = PKH(acc[4][2*h],   acc[5][2*h]);
            v2h ca3 = PKH(acc[6][2*h],   acc[7][2*h]);
            v2h ca4 = PKH(acc[8][2*h],   0.f);
            v2h cb0 = PKH(acc[0][2*h+1], acc[1][2*h+1]);
            v2h cb1 = PKH(acc[2][2*h+1], acc[3][2*h+1]);
            v2h cb2 = PKH(acc[4][2*h+1], acc[5][2*h+1]);
            v2h cb3 = PKH(acc[6][2*h+1], acc[7][2*h+1]);
            v2h cb4 = PKH(acc[8][2*h+1], 0.f);
            float t0[9], t1[9];
            #pragma unroll
            for (int i = 0; i < 9; ++i) {
                const float* row = g + O_U + (h * 9 + i) * 5;
                U1 r0, r1, r2, r3, r4;
                r0.f = row[0]; r1.f = row[1]; r2.f = row[2];
                r3.f = row[3]; r4.f = row[4];
                float s0 = 0.f, s1 = 0.f;
                s0 = FDOT2(r0.h, ca0, s0); s1 = FDOT2(r0.h, cb0, s1);
                s0 = FDOT2(r1.h, ca1, s0); s1 = FDOT2(r1.h, cb1, s1);
                s0 = FDOT2(r2.h, ca2, s0); s1 = FDOT2(r2.h, cb2, s1);
                s0 = FDOT2(r3.h, ca3, s0); s1 = FDOT2(r3.h, cb3, s1);
                s0 = FDOT2(r4.h, ca4, s0); s1 = FDOT2(r4.h, cb4, s1);
                t0[i] = s0; t1[i] = s1;
            }
            #pragma unroll
            for (int i = 0; i < 9; ++i) { acc[i][2 * h] = t0[i]; acc[i][2 * h + 1] = t1[i]; }
        }

        // ---- F0: pack h2 to f16 pair-slots in LDS (overlay at group base) ----
        #pragma unroll
        for (int n = 0; n < 9; ++n) {
            #pragma unroll
            for (int kp = 0; kp < 3; ++kp) {
                U1 u; u.h = PKH(acc[n][2 * kp], acc[n][2 * kp + 1]);
                ((float*)g)[n * 24 + 3 * l8 + kp] = u.f;
            }
        }
        WAVE_SYNC();

        // ---- F+G: scores via dot2 against pre-packed Wp1; butterfly once per n ----
        float sp[9];
        #pragma unroll
        for (int n = 0; n < 9; ++n) sp[n] = 0.f;
        #pragma unroll
        for (int kk = 0; kk < 3; ++kk) {
            int k = l8 + 8 * kk;
            float wqv = Wp2[k];
            float bqv = bp1[k];
            U4 w0, w1, w2u, w3, w4, w5;
            w0.f = wsf4[576 + k * 6 + 0];
            w1.f = wsf4[576 + k * 6 + 1];
            w2u.f = wsf4[576 + k * 6 + 2];
            w3.f = wsf4[576 + k * 6 + 3];
            w4.f = wsf4[576 + k * 6 + 4];
            w5.f = wsf4[576 + k * 6 + 5];
            #pragma unroll
            for (int n = 0; n < 9; ++n) {
                float a = 0.f;
                U4 x;
                x.f = h2f4[n * 6 + 0];
                a = FDOT2(x.h[0], w0.h[0], a); a = FDOT2(x.h[1], w0.h[1], a);
                a = FDOT2(x.h[2], w0.h[2], a); a = FDOT2(x.h[3], w0.h[3], a);
                x.f = h2f4[n * 6 + 1];
                a = FDOT2(x.h[0], w1.h[0], a); a = FDOT2(x.h[1], w1.h[1], a);
                a = FDOT2(x.h[2], w1.h[2], a); a = FDOT2(x.h[3], w1.h[3], a);
                x.f = h2f4[n * 6 + 2];
                a = FDOT2(x.h[0], w2u.h[0], a); a = FDOT2(x.h[1], w2u.h[1], a);
                a = FDOT2(x.h[2], w2u.h[2], a); a = FDOT2(x.h[3], w2u.h[3], a);
                x.f = h2f4[n * 6 + 3];
                a = FDOT2(x.h[0], w3.h[0], a); a = FDOT2(x.h[1], w3.h[1], a);
                a = FDOT2(x.h[2], w3.h[2], a); a = FDOT2(x.h[3], w3.h[3], a);
                x.f = h2f4[n * 6 + 4];
                a = FDOT2(x.h[0], w4.h[0], a); a = FDOT2(x.h[1], w4.h[1], a);
                a = FDOT2(x.h[2], w4.h[2], a); a = FDOT2(x.h[3], w4.h[3], a);
                x.f = h2f4[n * 6 + 5];
                a = FDOT2(x.h[0], w5.h[0], a); a = FDOT2(x.h[1], w5.h[1], a);
                a = FDOT2(x.h[2], w5.h[2], a); a = FDOT2(x.h[3], w5.h[3], a);
                float tv = tanh_fast(a + bqv);
                sp[n] += tv * wqv;
            }
        }
        #pragma unroll
        for (int n = 0; n < 9; ++n) {
            sp[n] += __shfl_xor(sp[n], 1, 8);
            sp[n] += __shfl_xor(sp[n], 2, 8);
            sp[n] += __shfl_xor(sp[n], 4, 8);
        }

        // ---- H: node softmax (bp2 cancels) + weighted sum -> out ----
        float mx = sp[0];
        #pragma unroll
        for (int n = 1; n < 9; ++n) mx = fmaxf(mx, sp[n]);
        float wn9[9], sum = 0.f;
        #pragma unroll
        for (int n = 0; n < 9; ++n) { wn9[n] = __expf(sp[n] - mx); sum += wn9[n]; }
        float r = fast_rcp(sum);
        #pragma unroll
        for (int k = 0; k < 6; ++k) {
            float ov = 0.f;
            #pragma unroll
            for (int n = 0; n < 9; ++n) ov += wn9[n] * acc[n][k];
            out[(size_t)b * 48 + l8 + 8 * k] = ov * r;
        }
        WAVE_SYNC();
    }
}

extern "C" void kernel_launch(void* const* d_in, const int* in_sizes, int n_in,
                              void* d_out, int out_size, void* d_ws, size_t ws_size,
                              hipStream_t stream) {
    const float* obs = (const float*)d_in[0];
    const float* adj = (const float*)d_in[1];
    const float* W1  = (const float*)d_in[2];
    const float* a1  = (const float*)d_in[3];
    const float* W2  = (const float*)d_in[4];
    const float* a2  = (const float*)d_in[5];
    const float* Wp1 = (const float*)d_in[6];
    const float* bp1 = (const float*)d_in[7];
    const float* Wp2 = (const float*)d_in[8];
    float* out = (float*)d_out;
    h16* ws = (h16*)d_ws;

    const int B = in_sizes[0] / 9;

    prep_kernel<<<(48 * 96 + 576 + 255) / 256, 256, 0, stream>>>(W2, Wp1, ws);

    gnn_gat_kernel<<<4096, 128, 0, stream>>>(
        obs, adj, W1, a1, a2, bp1, Wp2, ws, out, B);
}